// Round 1
// baseline (1879.054 us; speedup 1.0000x reference)
//
#include <hip/hip_runtime.h>

constexpr int NN = 100000;   // nodes
constexpr int NE = 1600000;  // edges
constexpr int NG = 256;      // graphs
// dims: layer1 in=128, all out=64

// ---------------- degree / dinv ----------------
__global__ void k_init_deg(float* deg) {
  int i = blockIdx.x * 256 + threadIdx.x;
  if (i < NN) deg[i] = 1.0f;  // self-loop
}

__global__ void k_count_deg(const int* __restrict__ ei, float* deg) {
  int e = blockIdx.x * 256 + threadIdx.x;
  if (e < NE) unsafeAtomicAdd(&deg[ei[NE + e]], 1.0f);
}

__global__ void k_rsqrt(float* deg) {
  int i = blockIdx.x * 256 + threadIdx.x;
  if (i < NN) deg[i] = rsqrtf(deg[i]);
}

// ---------------- dense GEMM: h[N][64] = in[N][K] @ W[K][64] ----------------
template <int K>
__global__ __launch_bounds__(256) void k_gemm(const float* __restrict__ in,
                                              const float* __restrict__ W,
                                              float* __restrict__ h) {
  __shared__ float Wl[K * 64];
  __shared__ float xr[4][4][K];  // [wave][subrow][K]
  for (int idx = threadIdx.x; idx < K * 64; idx += 256) Wl[idx] = W[idx];
  __syncthreads();
  const int lane = threadIdx.x & 63;
  const int wv = threadIdx.x >> 6;
  for (int base = blockIdx.x * 16; base < NN; base += gridDim.x * 16) {
    int r0 = base + wv * 4;
#pragma unroll
    for (int j = 0; j < 4; j++) {
      int row = r0 + j;
      float v0 = 0.f, v1 = 0.f;
      if (row < NN) {
        v0 = in[(long)row * K + lane];
        if (K == 128) v1 = in[(long)row * K + 64 + lane];
      }
      xr[wv][j][lane] = v0;
      if (K == 128) xr[wv][j][64 + lane] = v1;
    }
    // LDS ops from the same wave are processed in order: no barrier needed.
    float acc0 = 0, acc1 = 0, acc2 = 0, acc3 = 0;
    const float4* x0 = (const float4*)xr[wv][0];
    const float4* x1 = (const float4*)xr[wv][1];
    const float4* x2 = (const float4*)xr[wv][2];
    const float4* x3 = (const float4*)xr[wv][3];
#pragma unroll 4
    for (int k4 = 0; k4 < K / 4; k4++) {
      float4 a0 = x0[k4], a1 = x1[k4], a2 = x2[k4], a3 = x3[k4];
      float w0 = Wl[(4 * k4 + 0) * 64 + lane];
      float w1 = Wl[(4 * k4 + 1) * 64 + lane];
      float w2 = Wl[(4 * k4 + 2) * 64 + lane];
      float w3 = Wl[(4 * k4 + 3) * 64 + lane];
      acc0 += a0.x * w0 + a0.y * w1 + a0.z * w2 + a0.w * w3;
      acc1 += a1.x * w0 + a1.y * w1 + a1.z * w2 + a1.w * w3;
      acc2 += a2.x * w0 + a2.y * w1 + a2.z * w2 + a2.w * w3;
      acc3 += a3.x * w0 + a3.y * w1 + a3.z * w2 + a3.w * w3;
    }
    if (r0 + 0 < NN) h[(long)(r0 + 0) * 64 + lane] = acc0;
    if (r0 + 1 < NN) h[(long)(r0 + 1) * 64 + lane] = acc1;
    if (r0 + 2 < NN) h[(long)(r0 + 2) * 64 + lane] = acc2;
    if (r0 + 3 < NN) h[(long)(r0 + 3) * 64 + lane] = acc3;
  }
}

// ---------------- agg = h * dinv^2 (self-loop term, full init of agg) -------
__global__ void k_selfloop(const float4* __restrict__ h4, const float* __restrict__ dinv,
                           float4* __restrict__ agg4) {
  int i = blockIdx.x * 256 + threadIdx.x;  // over NN*16 float4s
  if (i < NN * 16) {
    int row = i >> 4;
    float dv = dinv[row];
    float s = dv * dv;
    float4 v = h4[i];
    v.x *= s; v.y *= s; v.z *= s; v.w *= s;
    agg4[i] = v;
  }
}

// ---------------- edge scatter: agg[dst] += h[src]*dinv[src]*dinv[dst] ------
__global__ __launch_bounds__(256) void k_scatter(const int* __restrict__ ei,
                                                 const float* __restrict__ dinv,
                                                 const float* __restrict__ h,
                                                 float* __restrict__ agg) {
  int tid = blockIdx.x * 256 + threadIdx.x;  // one edge per thread (for idx/norm)
  int lane = tid & 63;
  int s = ei[tid];
  int d = ei[NE + tid];
  float nrm = dinv[s] * dinv[d];
#pragma unroll 1
  for (int j = 0; j < 64; j++) {
    int sj = __shfl(s, j);
    int dj = __shfl(d, j);
    float nj = __shfl(nrm, j);
    float val = h[(long)sj * 64 + lane] * nj;
    unsafeAtomicAdd(&agg[(long)dj * 64 + lane], val);
  }
}

// ---------------- per-column sum / sumsq ----------------
__global__ void k_stats(const float* __restrict__ agg, float* __restrict__ stats) {
  __shared__ float ss[256], sq[256];
  int t = threadIdx.x;
  int c = t & 63, rg = t >> 6;
  float s = 0.f, q = 0.f;
  for (int r = blockIdx.x * 4 + rg; r < NN; r += gridDim.x * 4) {
    float v = agg[(long)r * 64 + c];
    s += v;
    q += v * v;
  }
  ss[t] = s; sq[t] = q;
  __syncthreads();
  if (t < 64) {
    s = ss[t] + ss[t + 64] + ss[t + 128] + ss[t + 192];
    q = sq[t] + sq[t + 64] + sq[t + 128] + sq[t + 192];
    unsafeAtomicAdd(&stats[c], s);
    unsafeAtomicAdd(&stats[64 + c], q);
  }
}

// ---------------- BN params: scale/shift per column ----------------
__global__ void k_bnparams(const float* __restrict__ stats, const float* __restrict__ gam,
                           const float* __restrict__ bet, float* __restrict__ bnp) {
  int c = threadIdx.x;
  if (c < 64) {
    const float inv_n = 1.0f / NN;
    float mean = stats[c] * inv_n;
    float var = stats[64 + c] * inv_n - mean * mean;
    float sc = gam[c] * rsqrtf(var + 1e-5f);
    bnp[c] = sc;
    bnp[64 + c] = bet[c] - mean * sc;  // note: conv bias cancels in BN
  }
}

// ---------------- y = relu(agg*scale + shift), in place ----------------
__global__ void k_apply(float4* __restrict__ a4, const float* __restrict__ bnp) {
  int i = blockIdx.x * 256 + threadIdx.x;
  if (i < NN * 16) {
    int c4 = (i & 15) * 4;
    float4 v = a4[i];
    v.x = fmaxf(v.x * bnp[c4 + 0] + bnp[64 + c4 + 0], 0.f);
    v.y = fmaxf(v.y * bnp[c4 + 1] + bnp[64 + c4 + 1], 0.f);
    v.z = fmaxf(v.z * bnp[c4 + 2] + bnp[64 + c4 + 2], 0.f);
    v.w = fmaxf(v.w * bnp[c4 + 3] + bnp[64 + c4 + 3], 0.f);
    a4[i] = v;
  }
}

// ---------------- layer-3 apply fused with mean-pool accumulation ----------
__global__ void k_apply_pool(const float* __restrict__ agg, const float* __restrict__ bnp,
                             const int* __restrict__ batch,
                             float* __restrict__ pool, float* __restrict__ cnt) {
  int i = blockIdx.x * 256 + threadIdx.x;
  if (i < NN * 64) {
    int c = i & 63, r = i >> 6;
    int g = batch[r];
    float v = fmaxf(agg[i] * bnp[c] + bnp[64 + c], 0.f);
    unsafeAtomicAdd(&pool[g * 64 + c], v);
    if (c == 0) unsafeAtomicAdd(&cnt[g], 1.0f);
  }
}

__global__ void k_finalize(const float* __restrict__ pool, const float* __restrict__ cnt,
                           float* __restrict__ out) {
  int i = blockIdx.x * 256 + threadIdx.x;
  if (i < NG * 64) out[i] = pool[i] / fmaxf(cnt[i >> 6], 1.0f);
}

extern "C" void kernel_launch(void* const* d_in, const int* in_sizes, int n_in,
                              void* d_out, int out_size, void* d_ws, size_t ws_size,
                              hipStream_t stream) {
  const float* x = (const float*)d_in[0];
  const int* ei = (const int*)d_in[1];
  const int* batch = (const int*)d_in[3];
  const float* W1 = (const float*)d_in[4];
  const float* g1 = (const float*)d_in[6];
  const float* be1 = (const float*)d_in[7];
  const float* W2 = (const float*)d_in[8];
  const float* g2 = (const float*)d_in[10];
  const float* be2 = (const float*)d_in[11];
  const float* W3 = (const float*)d_in[12];
  const float* g3 = (const float*)d_in[14];
  const float* be3 = (const float*)d_in[15];
  float* out = (float*)d_out;

  float* ws = (float*)d_ws;
  float* dinv = ws;                         // NN
  float* A = ws + NN;                       // NN*64  (h)
  float* B = A + (size_t)NN * 64;           // NN*64  (agg / y)
  float* stats = B + (size_t)NN * 64;       // 128
  float* bnp = stats + 128;                 // 128
  float* pool = bnp + 128;                  // NG*64
  float* cnt = pool + NG * 64;              // NG

  k_init_deg<<<(NN + 255) / 256, 256, 0, stream>>>(dinv);
  k_count_deg<<<NE / 256, 256, 0, stream>>>(ei, dinv);
  k_rsqrt<<<(NN + 255) / 256, 256, 0, stream>>>(dinv);

  const float* gs[3] = {g1, g2, g3};
  const float* bes[3] = {be1, be2, be3};
  const float* Wsr[3] = {W1, W2, W3};

  for (int layer = 0; layer < 3; layer++) {
    if (layer == 0)
      k_gemm<128><<<1024, 256, 0, stream>>>(x, Wsr[0], A);
    else
      k_gemm<64><<<1024, 256, 0, stream>>>(B, Wsr[layer], A);
    k_selfloop<<<NN * 16 / 256 + 1, 256, 0, stream>>>((const float4*)A, dinv, (float4*)B);
    k_scatter<<<NE / 256, 256, 0, stream>>>(ei, dinv, A, B);
    hipMemsetAsync(stats, 0, 128 * sizeof(float), stream);
    k_stats<<<256, 256, 0, stream>>>(B, stats);
    k_bnparams<<<1, 64, 0, stream>>>(stats, gs[layer], bes[layer], bnp);
    if (layer < 2) {
      k_apply<<<NN * 16 / 256 + 1, 256, 0, stream>>>((float4*)B, bnp);
    } else {
      hipMemsetAsync(pool, 0, (NG * 64 + NG) * sizeof(float), stream);
      k_apply_pool<<<NN * 64 / 256, 256, 0, stream>>>(B, bnp, batch, pool, cnt);
      k_finalize<<<(NG * 64 + 255) / 256, 256, 0, stream>>>(pool, cnt, out);
    }
  }
}

// Round 2
// 1537.468 us; speedup vs baseline: 1.2222x; 1.2222x over previous
//
#include <hip/hip_runtime.h>

constexpr int NN = 100000;   // nodes
constexpr int NE = 1600000;  // edges
constexpr int NG = 256;      // graphs
// dims: layer1 in=128, all out=64

// ---------------- degree / dinv ----------------
__global__ void k_init_deg(float* deg) {
  int i = blockIdx.x * 256 + threadIdx.x;
  if (i < NN) deg[i] = 1.0f;  // self-loop
}

__global__ void k_count_deg(const int* __restrict__ ei, float* deg) {
  int e = blockIdx.x * 256 + threadIdx.x;
  if (e < NE) unsafeAtomicAdd(&deg[ei[NE + e]], 1.0f);
}

__global__ void k_rsqrt(float* deg) {
  int i = blockIdx.x * 256 + threadIdx.x;
  if (i < NN) deg[i] = rsqrtf(deg[i]);
}

// ---------------- dense GEMM: h[N][64] = in[N][K] @ W[K][64] ----------------
template <int K>
__global__ __launch_bounds__(256) void k_gemm(const float* __restrict__ in,
                                              const float* __restrict__ W,
                                              float* __restrict__ h) {
  __shared__ float Wl[K * 64];
  __shared__ float xr[4][4][K];  // [wave][subrow][K]
  for (int idx = threadIdx.x; idx < K * 64; idx += 256) Wl[idx] = W[idx];
  __syncthreads();
  const int lane = threadIdx.x & 63;
  const int wv = threadIdx.x >> 6;
  for (int base = blockIdx.x * 16; base < NN; base += gridDim.x * 16) {
    int r0 = base + wv * 4;
#pragma unroll
    for (int j = 0; j < 4; j++) {
      int row = r0 + j;
      float v0 = 0.f, v1 = 0.f;
      if (row < NN) {
        v0 = in[(long)row * K + lane];
        if (K == 128) v1 = in[(long)row * K + 64 + lane];
      }
      xr[wv][j][lane] = v0;
      if (K == 128) xr[wv][j][64 + lane] = v1;
    }
    // LDS ops from the same wave are processed in order: no barrier needed.
    float acc0 = 0, acc1 = 0, acc2 = 0, acc3 = 0;
    const float4* x0 = (const float4*)xr[wv][0];
    const float4* x1 = (const float4*)xr[wv][1];
    const float4* x2 = (const float4*)xr[wv][2];
    const float4* x3 = (const float4*)xr[wv][3];
#pragma unroll 4
    for (int k4 = 0; k4 < K / 4; k4++) {
      float4 a0 = x0[k4], a1 = x1[k4], a2 = x2[k4], a3 = x3[k4];
      float w0 = Wl[(4 * k4 + 0) * 64 + lane];
      float w1 = Wl[(4 * k4 + 1) * 64 + lane];
      float w2 = Wl[(4 * k4 + 2) * 64 + lane];
      float w3 = Wl[(4 * k4 + 3) * 64 + lane];
      acc0 += a0.x * w0 + a0.y * w1 + a0.z * w2 + a0.w * w3;
      acc1 += a1.x * w0 + a1.y * w1 + a1.z * w2 + a1.w * w3;
      acc2 += a2.x * w0 + a2.y * w1 + a2.z * w2 + a2.w * w3;
      acc3 += a3.x * w0 + a3.y * w1 + a3.z * w2 + a3.w * w3;
    }
    if (r0 + 0 < NN) h[(long)(r0 + 0) * 64 + lane] = acc0;
    if (r0 + 1 < NN) h[(long)(r0 + 1) * 64 + lane] = acc1;
    if (r0 + 2 < NN) h[(long)(r0 + 2) * 64 + lane] = acc2;
    if (r0 + 3 < NN) h[(long)(r0 + 3) * 64 + lane] = acc3;
  }
}

// ---------------- agg = h * dinv^2 (self-loop term, full init of agg) -------
__global__ void k_selfloop(const float4* __restrict__ h4, const float* __restrict__ dinv,
                           float4* __restrict__ agg4) {
  int i = blockIdx.x * 256 + threadIdx.x;  // over NN*16 float4s
  if (i < NN * 16) {
    int row = i >> 4;
    float dv = dinv[row];
    float s = dv * dv;
    float4 v = h4[i];
    v.x *= s; v.y *= s; v.z *= s; v.w *= s;
    agg4[i] = v;
  }
}

// ---------------- edge scatter: agg[dst] += h[src]*dinv[src]*dinv[dst] ------
__global__ __launch_bounds__(256) void k_scatter(const int* __restrict__ ei,
                                                 const float* __restrict__ dinv,
                                                 const float* __restrict__ h,
                                                 float* __restrict__ agg) {
  int tid = blockIdx.x * 256 + threadIdx.x;  // one edge per thread (for idx/norm)
  int lane = tid & 63;
  int s = ei[tid];
  int d = ei[NE + tid];
  float nrm = dinv[s] * dinv[d];
#pragma unroll 1
  for (int j = 0; j < 64; j++) {
    int sj = __shfl(s, j);
    int dj = __shfl(d, j);
    float nj = __shfl(nrm, j);
    float val = h[(long)sj * 64 + lane] * nj;
    unsafeAtomicAdd(&agg[(long)dj * 64 + lane], val);
  }
}

// ---------------- per-column sum / sumsq ----------------
__global__ void k_stats(const float* __restrict__ agg, float* __restrict__ stats) {
  __shared__ float ss[256], sq[256];
  int t = threadIdx.x;
  int c = t & 63, rg = t >> 6;
  float s = 0.f, q = 0.f;
  for (int r = blockIdx.x * 4 + rg; r < NN; r += gridDim.x * 4) {
    float v = agg[(long)r * 64 + c];
    s += v;
    q += v * v;
  }
  ss[t] = s; sq[t] = q;
  __syncthreads();
  if (t < 64) {
    s = ss[t] + ss[t + 64] + ss[t + 128] + ss[t + 192];
    q = sq[t] + sq[t + 64] + sq[t + 128] + sq[t + 192];
    unsafeAtomicAdd(&stats[c], s);
    unsafeAtomicAdd(&stats[64 + c], q);
  }
}

// ---------------- BN params: scale/shift per column ----------------
__global__ void k_bnparams(const float* __restrict__ stats, const float* __restrict__ gam,
                           const float* __restrict__ bet, float* __restrict__ bnp) {
  int c = threadIdx.x;
  if (c < 64) {
    const float inv_n = 1.0f / NN;
    float mean = stats[c] * inv_n;
    float var = stats[64 + c] * inv_n - mean * mean;
    float sc = gam[c] * rsqrtf(var + 1e-5f);
    bnp[c] = sc;
    bnp[64 + c] = bet[c] - mean * sc;  // note: conv bias cancels in BN
  }
}

// ---------------- y = relu(agg*scale + shift), in place ----------------
__global__ void k_apply(float4* __restrict__ a4, const float* __restrict__ bnp) {
  int i = blockIdx.x * 256 + threadIdx.x;
  if (i < NN * 16) {
    int c4 = (i & 15) * 4;
    float4 v = a4[i];
    v.x = fmaxf(v.x * bnp[c4 + 0] + bnp[64 + c4 + 0], 0.f);
    v.y = fmaxf(v.y * bnp[c4 + 1] + bnp[64 + c4 + 1], 0.f);
    v.z = fmaxf(v.z * bnp[c4 + 2] + bnp[64 + c4 + 2], 0.f);
    v.w = fmaxf(v.w * bnp[c4 + 3] + bnp[64 + c4 + 3], 0.f);
    a4[i] = v;
  }
}

// ---------------- layer-3 apply fused with mean-pool (segmented: batch is sorted) ----
// One wave = 64 columns. Each wave owns a contiguous chunk of rows, accumulates
// in a register while batch[r] is constant, flushes one atomic per segment.
__global__ __launch_bounds__(256) void k_apply_pool(const float* __restrict__ agg,
                                                    const float* __restrict__ bnp,
                                                    const int* __restrict__ batch,
                                                    float* __restrict__ pool,
                                                    float* __restrict__ cnt) {
  const int lane = threadIdx.x & 63;
  const int wave = blockIdx.x * 4 + (threadIdx.x >> 6);
  const int nwaves = gridDim.x * 4;
  const int chunk = (NN + nwaves - 1) / nwaves;
  int r0 = wave * chunk;
  int r1 = min(r0 + chunk, NN);
  if (r0 >= r1) return;
  const float sc = bnp[lane], sh = bnp[64 + lane];
  int cur = batch[r0];
  float acc = 0.f;
  float runlen = 0.f;
#pragma unroll 1
  for (int r = r0; r < r1; r++) {
    int g = batch[r];
    if (g != cur) {
      unsafeAtomicAdd(&pool[cur * 64 + lane], acc);
      if (lane == 0) unsafeAtomicAdd(&cnt[cur], runlen);
      acc = 0.f; runlen = 0.f; cur = g;
    }
    acc += fmaxf(agg[(long)r * 64 + lane] * sc + sh, 0.f);
    runlen += 1.f;
  }
  unsafeAtomicAdd(&pool[cur * 64 + lane], acc);
  if (lane == 0) unsafeAtomicAdd(&cnt[cur], runlen);
}

__global__ void k_finalize(const float* __restrict__ pool, const float* __restrict__ cnt,
                           float* __restrict__ out) {
  int i = blockIdx.x * 256 + threadIdx.x;
  if (i < NG * 64) out[i] = pool[i] / fmaxf(cnt[i >> 6], 1.0f);
}

extern "C" void kernel_launch(void* const* d_in, const int* in_sizes, int n_in,
                              void* d_out, int out_size, void* d_ws, size_t ws_size,
                              hipStream_t stream) {
  const float* x = (const float*)d_in[0];
  const int* ei = (const int*)d_in[1];
  const int* batch = (const int*)d_in[3];
  const float* W1 = (const float*)d_in[4];
  const float* g1 = (const float*)d_in[6];
  const float* be1 = (const float*)d_in[7];
  const float* W2 = (const float*)d_in[8];
  const float* g2 = (const float*)d_in[10];
  const float* be2 = (const float*)d_in[11];
  const float* W3 = (const float*)d_in[12];
  const float* g3 = (const float*)d_in[14];
  const float* be3 = (const float*)d_in[15];
  float* out = (float*)d_out;

  float* ws = (float*)d_ws;
  float* dinv = ws;                         // NN
  float* A = ws + NN;                       // NN*64  (h)
  float* B = A + (size_t)NN * 64;           // NN*64  (agg / y)
  float* stats = B + (size_t)NN * 64;       // 128
  float* bnp = stats + 128;                 // 128
  float* pool = bnp + 128;                  // NG*64
  float* cnt = pool + NG * 64;              // NG

  k_init_deg<<<(NN + 255) / 256, 256, 0, stream>>>(dinv);
  k_count_deg<<<NE / 256, 256, 0, stream>>>(ei, dinv);
  k_rsqrt<<<(NN + 255) / 256, 256, 0, stream>>>(dinv);

  const float* gs[3] = {g1, g2, g3};
  const float* bes[3] = {be1, be2, be3};
  const float* Wsr[3] = {W1, W2, W3};

  for (int layer = 0; layer < 3; layer++) {
    if (layer == 0)
      k_gemm<128><<<1024, 256, 0, stream>>>(x, Wsr[0], A);
    else
      k_gemm<64><<<1024, 256, 0, stream>>>(B, Wsr[layer], A);
    k_selfloop<<<NN * 16 / 256 + 1, 256, 0, stream>>>((const float4*)A, dinv, (float4*)B);
    k_scatter<<<NE / 256, 256, 0, stream>>>(ei, dinv, A, B);
    hipMemsetAsync(stats, 0, 128 * sizeof(float), stream);
    k_stats<<<256, 256, 0, stream>>>(B, stats);
    k_bnparams<<<1, 64, 0, stream>>>(stats, gs[layer], bes[layer], bnp);
    if (layer < 2) {
      k_apply<<<NN * 16 / 256 + 1, 256, 0, stream>>>((float4*)B, bnp);
    } else {
      hipMemsetAsync(pool, 0, (NG * 64 + NG) * sizeof(float), stream);
      k_apply_pool<<<1024, 256, 0, stream>>>(B, bnp, batch, pool, cnt);
      k_finalize<<<(NG * 64 + 255) / 256, 256, 0, stream>>>(pool, cnt, out);
    }
  }
}

// Round 3
// 945.470 us; speedup vs baseline: 1.9874x; 1.6261x over previous
//
#include <hip/hip_runtime.h>

constexpr int NN = 100000;   // nodes
constexpr int NE = 1600000;  // edges
constexpr int NG = 256;      // graphs
constexpr int GGRID = 1024;  // gather grid (blocks)
constexpr int NB_SCAN = (NN + 255) / 256;  // 391

// ---------------- CSR build ----------------
__global__ void k_hist(const int* __restrict__ ei, int* __restrict__ hist) {
  int e = blockIdx.x * 256 + threadIdx.x;
  if (e < NE) atomicAdd(&hist[ei[NE + e]], 1);
}

__global__ void k_dinv(const int* __restrict__ hist, float* __restrict__ dinv) {
  int i = blockIdx.x * 256 + threadIdx.x;
  if (i < NN) dinv[i] = rsqrtf((float)(hist[i] + 1));  // +1 self-loop
}

__global__ void k_scan_local(const int* __restrict__ hist, int* __restrict__ rs,
                             int* __restrict__ bsum) {
  __shared__ int s[256];
  int t = threadIdx.x, idx = blockIdx.x * 256 + t;
  int v = (idx < NN) ? hist[idx] : 0;
  s[t] = v;
  __syncthreads();
  for (int off = 1; off < 256; off <<= 1) {
    int x = (t >= off) ? s[t - off] : 0;
    __syncthreads();
    if (t >= off) s[t] += x;
    __syncthreads();
  }
  if (idx < NN) rs[idx] = s[t] - v;  // exclusive
  if (t == 255) bsum[blockIdx.x] = s[255];
}

__global__ void k_scan_bsum(int* __restrict__ bsum, int* __restrict__ boff) {
  __shared__ int s[512];
  int t = threadIdx.x;
  int v = (t < NB_SCAN) ? bsum[t] : 0;
  s[t] = v;
  __syncthreads();
  for (int off = 1; off < 512; off <<= 1) {
    int x = (t >= off) ? s[t - off] : 0;
    __syncthreads();
    if (t >= off) s[t] += x;
    __syncthreads();
  }
  boff[t] = s[t] - v;  // exclusive
}

__global__ void k_scan_add(int* __restrict__ rs, const int* __restrict__ boff) {
  int idx = blockIdx.x * 256 + threadIdx.x;
  if (idx < NN) rs[idx] += boff[idx >> 8];
  if (idx == 0) rs[NN] = NE;
}

__global__ void k_fill(const int* __restrict__ ei, const float* __restrict__ dinv,
                       int* __restrict__ cursor, int2* __restrict__ edata) {
  int e = blockIdx.x * 256 + threadIdx.x;
  if (e < NE) {
    int s = ei[e], d = ei[NE + e];
    int pos = atomicAdd(&cursor[d], 1);
    edata[pos] = make_int2(s, __float_as_int(dinv[s] * dinv[d]));
  }
}

// ---------------- dense GEMM: h[N][64] = f(in)[N][K] @ W[K][64] -------------
// BN=true: apply y = relu(in*sc[col]+sh[col]) on input load (fused BN+ReLU).
template <int K, bool BN>
__global__ __launch_bounds__(256) void k_gemm(const float* __restrict__ in,
                                              const float* __restrict__ bnp,
                                              const float* __restrict__ W,
                                              float* __restrict__ h) {
  __shared__ float Wl[K * 64];
  __shared__ float xr[4][4][K];  // [wave][subrow][K]
  for (int idx = threadIdx.x; idx < K * 64; idx += 256) Wl[idx] = W[idx];
  __syncthreads();
  const int lane = threadIdx.x & 63;
  const int wv = threadIdx.x >> 6;
  float sc = 0.f, sh = 0.f;
  if (BN) { sc = bnp[lane]; sh = bnp[64 + lane]; }
  for (int base = blockIdx.x * 16; base < NN; base += gridDim.x * 16) {
    int r0 = base + wv * 4;
#pragma unroll
    for (int j = 0; j < 4; j++) {
      int row = r0 + j;
      float v0 = 0.f, v1 = 0.f;
      if (row < NN) {
        v0 = in[(long)row * K + lane];
        if (K == 128) v1 = in[(long)row * K + 64 + lane];
      }
      if (BN) v0 = fmaxf(v0 * sc + sh, 0.f);
      xr[wv][j][lane] = v0;
      if (K == 128) xr[wv][j][64 + lane] = v1;
    }
    // Same-wave LDS ops complete in order: no barrier needed.
    float acc0 = 0, acc1 = 0, acc2 = 0, acc3 = 0;
    const float4* x0 = (const float4*)xr[wv][0];
    const float4* x1 = (const float4*)xr[wv][1];
    const float4* x2 = (const float4*)xr[wv][2];
    const float4* x3 = (const float4*)xr[wv][3];
#pragma unroll 4
    for (int k4 = 0; k4 < K / 4; k4++) {
      float4 a0 = x0[k4], a1 = x1[k4], a2 = x2[k4], a3 = x3[k4];
      float w0 = Wl[(4 * k4 + 0) * 64 + lane];
      float w1 = Wl[(4 * k4 + 1) * 64 + lane];
      float w2 = Wl[(4 * k4 + 2) * 64 + lane];
      float w3 = Wl[(4 * k4 + 3) * 64 + lane];
      acc0 += a0.x * w0 + a0.y * w1 + a0.z * w2 + a0.w * w3;
      acc1 += a1.x * w0 + a1.y * w1 + a1.z * w2 + a1.w * w3;
      acc2 += a2.x * w0 + a2.y * w1 + a2.z * w2 + a2.w * w3;
      acc3 += a3.x * w0 + a3.y * w1 + a3.z * w2 + a3.w * w3;
    }
    if (r0 + 0 < NN) h[(long)(r0 + 0) * 64 + lane] = acc0;
    if (r0 + 1 < NN) h[(long)(r0 + 1) * 64 + lane] = acc1;
    if (r0 + 2 < NN) h[(long)(r0 + 2) * 64 + lane] = acc2;
    if (r0 + 3 < NN) h[(long)(r0 + 3) * 64 + lane] = acc3;
  }
}

// ---------------- CSR gather: agg[n] = h[n]*dinv[n]^2 + sum h[src]*norm -----
// One wave per node (lane = column). Fused per-column BN stats via per-block
// partials (partial[col][block], col 0..63 = sum, 64..127 = sumsq).
__global__ __launch_bounds__(256) void k_gather(const float* __restrict__ h,
                                                const int2* __restrict__ edata,
                                                const int* __restrict__ rs,
                                                const float* __restrict__ dinv,
                                                float* __restrict__ agg,
                                                float* __restrict__ partial) {
  const int lane = threadIdx.x & 63;
  const int wave = blockIdx.x * 4 + (threadIdx.x >> 6);
  const int nwaves = GGRID * 4;
  const int chunk = (NN + nwaves - 1) / nwaves;
  int r0 = wave * chunk, r1 = min(r0 + chunk, NN);
  float ssum = 0.f, ssq = 0.f;
#pragma unroll 1
  for (int node = r0; node < r1; node++) {
    float dv = dinv[node];
    float acc = h[(long)node * 64 + lane] * dv * dv;
    int e = rs[node], e1 = rs[node + 1];
#pragma unroll 1
    for (; e + 2 <= e1; e += 2) {
      int2 a = edata[e], b = edata[e + 1];
      float va = h[(long)a.x * 64 + lane];
      float vb = h[(long)b.x * 64 + lane];
      acc += va * __int_as_float(a.y) + vb * __int_as_float(b.y);
    }
    if (e < e1) {
      int2 a = edata[e];
      acc += h[(long)a.x * 64 + lane] * __int_as_float(a.y);
    }
    agg[(long)node * 64 + lane] = acc;
    ssum += acc;
    ssq += acc * acc;
  }
  __shared__ float red[2][256];
  red[0][threadIdx.x] = ssum;
  red[1][threadIdx.x] = ssq;
  __syncthreads();
  if (threadIdx.x < 64) {
    int t = threadIdx.x;
    float s = red[0][t] + red[0][t + 64] + red[0][t + 128] + red[0][t + 192];
    float q = red[1][t] + red[1][t + 64] + red[1][t + 128] + red[1][t + 192];
    partial[(long)t * GGRID + blockIdx.x] = s;
    partial[(long)(64 + t) * GGRID + blockIdx.x] = q;
  }
}

// ---------------- reduce per-block partials -> stats[128] ----------------
__global__ void k_redstats(const float* __restrict__ partial, float* __restrict__ stats) {
  __shared__ float red[256];
  int c = blockIdx.x, t = threadIdx.x;
  float s = 0.f;
#pragma unroll
  for (int k = 0; k < GGRID / 256; k++) s += partial[(long)c * GGRID + k * 256 + t];
  red[t] = s;
  __syncthreads();
  for (int off = 128; off > 0; off >>= 1) {
    if (t < off) red[t] += red[t + off];
    __syncthreads();
  }
  if (t == 0) stats[c] = red[0];
}

// ---------------- BN params: scale/shift per column ----------------
__global__ void k_bnparams(const float* __restrict__ stats, const float* __restrict__ gam,
                           const float* __restrict__ bet, float* __restrict__ bnp) {
  int c = threadIdx.x;
  if (c < 64) {
    const float inv_n = 1.0f / NN;
    float mean = stats[c] * inv_n;
    float var = stats[64 + c] * inv_n - mean * mean;
    float sc = gam[c] * rsqrtf(var + 1e-5f);
    bnp[c] = sc;
    bnp[64 + c] = bet[c] - mean * sc;  // conv bias cancels in BN
  }
}

// ---------------- layer-3 apply fused with mean-pool (batch sorted) ---------
__global__ __launch_bounds__(256) void k_apply_pool(const float* __restrict__ agg,
                                                    const float* __restrict__ bnp,
                                                    const int* __restrict__ batch,
                                                    float* __restrict__ pool,
                                                    float* __restrict__ cnt) {
  const int lane = threadIdx.x & 63;
  const int wave = blockIdx.x * 4 + (threadIdx.x >> 6);
  const int nwaves = gridDim.x * 4;
  const int chunk = (NN + nwaves - 1) / nwaves;
  int r0 = wave * chunk;
  int r1 = min(r0 + chunk, NN);
  if (r0 >= r1) return;
  const float sc = bnp[lane], sh = bnp[64 + lane];
  int cur = batch[r0];
  float acc = 0.f, runlen = 0.f;
#pragma unroll 1
  for (int r = r0; r < r1; r++) {
    int g = batch[r];
    if (g != cur) {
      unsafeAtomicAdd(&pool[cur * 64 + lane], acc);
      if (lane == 0) unsafeAtomicAdd(&cnt[cur], runlen);
      acc = 0.f; runlen = 0.f; cur = g;
    }
    acc += fmaxf(agg[(long)r * 64 + lane] * sc + sh, 0.f);
    runlen += 1.f;
  }
  unsafeAtomicAdd(&pool[cur * 64 + lane], acc);
  if (lane == 0) unsafeAtomicAdd(&cnt[cur], runlen);
}

__global__ void k_finalize(const float* __restrict__ pool, const float* __restrict__ cnt,
                           float* __restrict__ out) {
  int i = blockIdx.x * 256 + threadIdx.x;
  if (i < NG * 64) out[i] = pool[i] / fmaxf(cnt[i >> 6], 1.0f);
}

extern "C" void kernel_launch(void* const* d_in, const int* in_sizes, int n_in,
                              void* d_out, int out_size, void* d_ws, size_t ws_size,
                              hipStream_t stream) {
  const float* x = (const float*)d_in[0];
  const int* ei = (const int*)d_in[1];
  const int* batch = (const int*)d_in[3];
  const float* W1 = (const float*)d_in[4];
  const float* g1 = (const float*)d_in[6];
  const float* be1 = (const float*)d_in[7];
  const float* W2 = (const float*)d_in[8];
  const float* g2 = (const float*)d_in[10];
  const float* be2 = (const float*)d_in[11];
  const float* W3 = (const float*)d_in[12];
  const float* g3 = (const float*)d_in[14];
  const float* be3 = (const float*)d_in[15];
  float* out = (float*)d_out;

  char* ws = (char*)d_ws;
  float* dinv = (float*)ws;                     ws += (size_t)NN * 4;
  float* A = (float*)ws;                        ws += (size_t)NN * 64 * 4;
  float* B = (float*)ws;                        ws += (size_t)NN * 64 * 4;
  int* hist = (int*)ws;                         ws += (size_t)NN * 4;
  int* rs = (int*)ws;                           ws += (size_t)(NN + 1) * 4;
  int* bsum = (int*)ws;                         ws += 512 * 4;
  int* boff = (int*)ws;                         ws += 512 * 4;
  int* cursor = (int*)ws;                       ws += (size_t)NN * 4;
  int2* edata = (int2*)ws;                      ws += (size_t)NE * 8;
  float* partial = (float*)ws;                  ws += (size_t)128 * GGRID * 4;
  float* stats = (float*)ws;                    ws += 128 * 4;
  float* bnp = (float*)ws;                      ws += 128 * 4;
  float* pool = (float*)ws;                     ws += (size_t)NG * 64 * 4;
  float* cnt = (float*)ws;                      ws += (size_t)NG * 4;

  // ---- CSR build (amortized over 3 layers) ----
  hipMemsetAsync(hist, 0, (size_t)NN * 4, stream);
  k_hist<<<(NE + 255) / 256, 256, 0, stream>>>(ei, hist);
  k_dinv<<<(NN + 255) / 256, 256, 0, stream>>>(hist, dinv);
  k_scan_local<<<NB_SCAN, 256, 0, stream>>>(hist, rs, bsum);
  k_scan_bsum<<<1, 512, 0, stream>>>(bsum, boff);
  k_scan_add<<<NB_SCAN, 256, 0, stream>>>(rs, boff);
  hipMemcpyAsync(cursor, rs, (size_t)NN * 4, hipMemcpyDeviceToDevice, stream);
  k_fill<<<(NE + 255) / 256, 256, 0, stream>>>(ei, dinv, cursor, edata);

  const float* gs[3] = {g1, g2, g3};
  const float* bes[3] = {be1, be2, be3};
  const float* Wsr[3] = {W1, W2, W3};

  for (int layer = 0; layer < 3; layer++) {
    if (layer == 0)
      k_gemm<128, false><<<1024, 256, 0, stream>>>(x, nullptr, Wsr[0], A);
    else
      k_gemm<64, true><<<1024, 256, 0, stream>>>(B, bnp, Wsr[layer], A);
    k_gather<<<GGRID, 256, 0, stream>>>(A, edata, rs, dinv, B, partial);
    k_redstats<<<128, 256, 0, stream>>>(partial, stats);
    k_bnparams<<<1, 64, 0, stream>>>(stats, gs[layer], bes[layer], bnp);
    if (layer == 2) {
      hipMemsetAsync(pool, 0, (size_t)(NG * 64 + NG) * 4, stream);
      k_apply_pool<<<1024, 256, 0, stream>>>(B, bnp, batch, pool, cnt);
      k_finalize<<<(NG * 64 + 255) / 256, 256, 0, stream>>>(pool, cnt, out);
    }
  }
}

// Round 4
// 684.807 us; speedup vs baseline: 2.7439x; 1.3806x over previous
//
#include <hip/hip_runtime.h>
#include <hip/hip_fp16.h>

constexpr int NN = 100000;   // nodes
constexpr int NE = 1600000;  // edges
constexpr int NG = 256;      // graphs
constexpr int GGRID = 2048;  // gather grid (blocks)
constexpr int NB_SCAN = (NN + 255) / 256;  // 391

// ---------------- CSR build ----------------
__global__ void k_hist(const int* __restrict__ ei, int* __restrict__ hist) {
  int e = blockIdx.x * 256 + threadIdx.x;
  if (e < NE) atomicAdd(&hist[ei[NE + e]], 1);
}

__global__ void k_dinv(const int* __restrict__ hist, float* __restrict__ dinv) {
  int i = blockIdx.x * 256 + threadIdx.x;
  if (i < NN) dinv[i] = rsqrtf((float)(hist[i] + 1));  // +1 self-loop
}

__global__ void k_scan_local(const int* __restrict__ hist, int* __restrict__ rs,
                             int* __restrict__ bsum) {
  __shared__ int s[256];
  int t = threadIdx.x, idx = blockIdx.x * 256 + t;
  int v = (idx < NN) ? hist[idx] : 0;
  s[t] = v;
  __syncthreads();
  for (int off = 1; off < 256; off <<= 1) {
    int x = (t >= off) ? s[t - off] : 0;
    __syncthreads();
    if (t >= off) s[t] += x;
    __syncthreads();
  }
  if (idx < NN) rs[idx] = s[t] - v;  // exclusive
  if (t == 255) bsum[blockIdx.x] = s[255];
}

__global__ void k_scan_bsum(int* __restrict__ bsum, int* __restrict__ boff) {
  __shared__ int s[512];
  int t = threadIdx.x;
  int v = (t < NB_SCAN) ? bsum[t] : 0;
  s[t] = v;
  __syncthreads();
  for (int off = 1; off < 512; off <<= 1) {
    int x = (t >= off) ? s[t - off] : 0;
    __syncthreads();
    if (t >= off) s[t] += x;
    __syncthreads();
  }
  boff[t] = s[t] - v;  // exclusive
}

__global__ void k_scan_add(int* __restrict__ rs, const int* __restrict__ boff) {
  int idx = blockIdx.x * 256 + threadIdx.x;
  if (idx < NN) rs[idx] += boff[idx >> 8];
  if (idx == 0) rs[NN] = NE;
}

__global__ void k_fill(const int* __restrict__ ei, const float* __restrict__ dinv,
                       int* __restrict__ cursor, int2* __restrict__ edata) {
  int e = blockIdx.x * 256 + threadIdx.x;
  if (e < NE) {
    int s = ei[e], d = ei[NE + e];
    int pos = atomicAdd(&cursor[d], 1);
    edata[pos] = make_int2(s, __float_as_int(dinv[s] * dinv[d]));
  }
}

// ---------------- dense GEMM: h[N][64] = f(in)[N][K] @ W[K][64], h in fp16 --
// BN=true: apply y = relu(in*sc[col]+sh[col]) on input load (fused BN+ReLU).
template <int K, bool BN>
__global__ __launch_bounds__(256) void k_gemm(const float* __restrict__ in,
                                              const float* __restrict__ bnp,
                                              const float* __restrict__ W,
                                              __half* __restrict__ h) {
  __shared__ float Wl[K * 64];
  __shared__ float xr[4][4][K];  // [wave][subrow][K]
  for (int idx = threadIdx.x; idx < K * 64; idx += 256) Wl[idx] = W[idx];
  __syncthreads();
  const int lane = threadIdx.x & 63;
  const int wv = threadIdx.x >> 6;
  float sc = 0.f, sh = 0.f;
  if (BN) { sc = bnp[lane]; sh = bnp[64 + lane]; }
  for (int base = blockIdx.x * 16; base < NN; base += gridDim.x * 16) {
    int r0 = base + wv * 4;
#pragma unroll
    for (int j = 0; j < 4; j++) {
      int row = r0 + j;
      float v0 = 0.f, v1 = 0.f;
      if (row < NN) {
        v0 = in[(long)row * K + lane];
        if (K == 128) v1 = in[(long)row * K + 64 + lane];
      }
      if (BN) v0 = fmaxf(v0 * sc + sh, 0.f);
      xr[wv][j][lane] = v0;
      if (K == 128) xr[wv][j][64 + lane] = v1;
    }
    // Same-wave LDS ops complete in order: no barrier needed.
    float acc0 = 0, acc1 = 0, acc2 = 0, acc3 = 0;
    const float4* x0 = (const float4*)xr[wv][0];
    const float4* x1 = (const float4*)xr[wv][1];
    const float4* x2 = (const float4*)xr[wv][2];
    const float4* x3 = (const float4*)xr[wv][3];
#pragma unroll 4
    for (int k4 = 0; k4 < K / 4; k4++) {
      float4 a0 = x0[k4], a1 = x1[k4], a2 = x2[k4], a3 = x3[k4];
      float w0 = Wl[(4 * k4 + 0) * 64 + lane];
      float w1 = Wl[(4 * k4 + 1) * 64 + lane];
      float w2 = Wl[(4 * k4 + 2) * 64 + lane];
      float w3 = Wl[(4 * k4 + 3) * 64 + lane];
      acc0 += a0.x * w0 + a0.y * w1 + a0.z * w2 + a0.w * w3;
      acc1 += a1.x * w0 + a1.y * w1 + a1.z * w2 + a1.w * w3;
      acc2 += a2.x * w0 + a2.y * w1 + a2.z * w2 + a2.w * w3;
      acc3 += a3.x * w0 + a3.y * w1 + a3.z * w2 + a3.w * w3;
    }
    if (r0 + 0 < NN) h[(long)(r0 + 0) * 64 + lane] = __float2half(acc0);
    if (r0 + 1 < NN) h[(long)(r0 + 1) * 64 + lane] = __float2half(acc1);
    if (r0 + 2 < NN) h[(long)(r0 + 2) * 64 + lane] = __float2half(acc2);
    if (r0 + 3 < NN) h[(long)(r0 + 3) * 64 + lane] = __float2half(acc3);
  }
}

// ---------------- CSR gather (fp16 h): agg[n] = h[n]*dinv^2 + sum h[s]*nrm --
// One wave per node; lane l32 owns column pair {2*l32, 2*l32+1} (__half2).
// The two half-waves process alternating edges (2 edges in flight), combined
// with one shfl at node end. Fused per-column BN stats via per-block partials.
__global__ __launch_bounds__(256) void k_gather(const __half* __restrict__ h,
                                                const int2* __restrict__ edata,
                                                const int* __restrict__ rs,
                                                const float* __restrict__ dinv,
                                                float* __restrict__ agg,
                                                float* __restrict__ partial) {
  const int lane = threadIdx.x & 63;
  const int l32 = lane & 31;
  const int hw = lane >> 5;
  const int wave = blockIdx.x * 4 + (threadIdx.x >> 6);
  const int nwaves = GGRID * 4;
  const int chunk = (NN + nwaves - 1) / nwaves;
  int r0 = wave * chunk, r1 = min(r0 + chunk, NN);
  float2 ssum = {0.f, 0.f}, ssq = {0.f, 0.f};
#pragma unroll 1
  for (int node = r0; node < r1; node++) {
    int e0 = rs[node], e1 = rs[node + 1];
    float2 acc = {0.f, 0.f};
    int e = e0 + hw;
#pragma unroll 1
    for (; e + 2 < e1; e += 4) {  // 2 edges per half-wave in flight
      int2 ea = edata[e], eb = edata[e + 2];
      float2 va = __half22float2(((const __half2*)(h + (long)ea.x * 64))[l32]);
      float2 vb = __half22float2(((const __half2*)(h + (long)eb.x * 64))[l32]);
      float na = __int_as_float(ea.y), nb = __int_as_float(eb.y);
      acc.x += va.x * na + vb.x * nb;
      acc.y += va.y * na + vb.y * nb;
    }
    if (e < e1) {
      int2 ea = edata[e];
      float2 va = __half22float2(((const __half2*)(h + (long)ea.x * 64))[l32]);
      float na = __int_as_float(ea.y);
      acc.x += va.x * na;
      acc.y += va.y * na;
    }
    // combine the two half-waves (both end with the full sum)
    float tx = __shfl(acc.x, lane ^ 32);
    float ty = __shfl(acc.y, lane ^ 32);
    acc.x += tx; acc.y += ty;
    // self-loop term
    float dv = dinv[node];
    float2 sv = __half22float2(((const __half2*)(h + (long)node * 64))[l32]);
    acc.x += sv.x * dv * dv;
    acc.y += sv.y * dv * dv;
    if (hw == 0) {
      ((float2*)(agg + (long)node * 64))[l32] = acc;
      ssum.x += acc.x; ssum.y += acc.y;
      ssq.x += acc.x * acc.x; ssq.y += acc.y * acc.y;
    }
  }
  __shared__ float red[2][4][64];
  const int wv = threadIdx.x >> 6;
  if (hw == 0) {
    red[0][wv][2 * l32] = ssum.x; red[0][wv][2 * l32 + 1] = ssum.y;
    red[1][wv][2 * l32] = ssq.x;  red[1][wv][2 * l32 + 1] = ssq.y;
  }
  __syncthreads();
  if (threadIdx.x < 128) {
    int s = threadIdx.x >> 6, c = threadIdx.x & 63;
    float v = red[s][0][c] + red[s][1][c] + red[s][2][c] + red[s][3][c];
    partial[(long)threadIdx.x * GGRID + blockIdx.x] = v;
  }
}

// ---------------- reduce per-block partials -> stats[128] ----------------
__global__ void k_redstats(const float* __restrict__ partial, float* __restrict__ stats) {
  __shared__ float red[256];
  int c = blockIdx.x, t = threadIdx.x;
  float s = 0.f;
#pragma unroll
  for (int k = 0; k < GGRID / 256; k++) s += partial[(long)c * GGRID + k * 256 + t];
  red[t] = s;
  __syncthreads();
  for (int off = 128; off > 0; off >>= 1) {
    if (t < off) red[t] += red[t + off];
    __syncthreads();
  }
  if (t == 0) stats[c] = red[0];
}

// ---------------- BN params: scale/shift per column ----------------
__global__ void k_bnparams(const float* __restrict__ stats, const float* __restrict__ gam,
                           const float* __restrict__ bet, float* __restrict__ bnp) {
  int c = threadIdx.x;
  if (c < 64) {
    const float inv_n = 1.0f / NN;
    float mean = stats[c] * inv_n;
    float var = stats[64 + c] * inv_n - mean * mean;
    float sc = gam[c] * rsqrtf(var + 1e-5f);
    bnp[c] = sc;
    bnp[64 + c] = bet[c] - mean * sc;  // conv bias cancels in BN
  }
}

// ---------------- layer-3 apply fused with mean-pool (batch sorted) ---------
__global__ __launch_bounds__(256) void k_apply_pool(const float* __restrict__ agg,
                                                    const float* __restrict__ bnp,
                                                    const int* __restrict__ batch,
                                                    float* __restrict__ pool,
                                                    float* __restrict__ cnt) {
  const int lane = threadIdx.x & 63;
  const int wave = blockIdx.x * 4 + (threadIdx.x >> 6);
  const int nwaves = gridDim.x * 4;
  const int chunk = (NN + nwaves - 1) / nwaves;
  int r0 = wave * chunk;
  int r1 = min(r0 + chunk, NN);
  if (r0 >= r1) return;
  const float sc = bnp[lane], sh = bnp[64 + lane];
  int cur = batch[r0];
  float acc = 0.f, runlen = 0.f;
#pragma unroll 1
  for (int r = r0; r < r1; r++) {
    int g = batch[r];
    if (g != cur) {
      unsafeAtomicAdd(&pool[cur * 64 + lane], acc);
      if (lane == 0) unsafeAtomicAdd(&cnt[cur], runlen);
      acc = 0.f; runlen = 0.f; cur = g;
    }
    acc += fmaxf(agg[(long)r * 64 + lane] * sc + sh, 0.f);
    runlen += 1.f;
  }
  unsafeAtomicAdd(&pool[cur * 64 + lane], acc);
  if (lane == 0) unsafeAtomicAdd(&cnt[cur], runlen);
}

__global__ void k_finalize(const float* __restrict__ pool, const float* __restrict__ cnt,
                           float* __restrict__ out) {
  int i = blockIdx.x * 256 + threadIdx.x;
  if (i < NG * 64) out[i] = pool[i] / fmaxf(cnt[i >> 6], 1.0f);
}

extern "C" void kernel_launch(void* const* d_in, const int* in_sizes, int n_in,
                              void* d_out, int out_size, void* d_ws, size_t ws_size,
                              hipStream_t stream) {
  const float* x = (const float*)d_in[0];
  const int* ei = (const int*)d_in[1];
  const int* batch = (const int*)d_in[3];
  const float* W1 = (const float*)d_in[4];
  const float* g1 = (const float*)d_in[6];
  const float* be1 = (const float*)d_in[7];
  const float* W2 = (const float*)d_in[8];
  const float* g2 = (const float*)d_in[10];
  const float* be2 = (const float*)d_in[11];
  const float* W3 = (const float*)d_in[12];
  const float* g3 = (const float*)d_in[14];
  const float* be3 = (const float*)d_in[15];
  float* out = (float*)d_out;

  char* ws = (char*)d_ws;
  float* dinv = (float*)ws;                     ws += (size_t)NN * 4;
  __half* A = (__half*)ws;                      ws += (size_t)NN * 64 * 2;  // h (fp16)
  float* B = (float*)ws;                        ws += (size_t)NN * 64 * 4;  // agg (fp32)
  int* hist = (int*)ws;                         ws += (size_t)NN * 4;
  int* rs = (int*)ws;                           ws += (size_t)(NN + 1) * 4;
  int* bsum = (int*)ws;                         ws += 512 * 4;
  int* boff = (int*)ws;                         ws += 512 * 4;
  int* cursor = (int*)ws;                       ws += (size_t)NN * 4;
  int2* edata = (int2*)ws;                      ws += (size_t)NE * 8;
  float* partial = (float*)ws;                  ws += (size_t)128 * GGRID * 4;
  float* stats = (float*)ws;                    ws += 128 * 4;
  float* bnp = (float*)ws;                      ws += 128 * 4;
  float* pool = (float*)ws;                     ws += (size_t)NG * 64 * 4;
  float* cnt = (float*)ws;                      ws += (size_t)NG * 4;

  // ---- CSR build (amortized over 3 layers) ----
  hipMemsetAsync(hist, 0, (size_t)NN * 4, stream);
  k_hist<<<(NE + 255) / 256, 256, 0, stream>>>(ei, hist);
  k_dinv<<<(NN + 255) / 256, 256, 0, stream>>>(hist, dinv);
  k_scan_local<<<NB_SCAN, 256, 0, stream>>>(hist, rs, bsum);
  k_scan_bsum<<<1, 512, 0, stream>>>(bsum, boff);
  k_scan_add<<<NB_SCAN, 256, 0, stream>>>(rs, boff);
  hipMemcpyAsync(cursor, rs, (size_t)NN * 4, hipMemcpyDeviceToDevice, stream);
  k_fill<<<(NE + 255) / 256, 256, 0, stream>>>(ei, dinv, cursor, edata);

  const float* gs[3] = {g1, g2, g3};
  const float* bes[3] = {be1, be2, be3};
  const float* Wsr[3] = {W1, W2, W3};

  for (int layer = 0; layer < 3; layer++) {
    if (layer == 0)
      k_gemm<128, false><<<1024, 256, 0, stream>>>(x, nullptr, Wsr[0], A);
    else
      k_gemm<64, true><<<1024, 256, 0, stream>>>(B, bnp, Wsr[layer], A);
    k_gather<<<GGRID, 256, 0, stream>>>(A, edata, rs, dinv, B, partial);
    k_redstats<<<128, 256, 0, stream>>>(partial, stats);
    k_bnparams<<<1, 64, 0, stream>>>(stats, gs[layer], bes[layer], bnp);
    if (layer == 2) {
      hipMemsetAsync(pool, 0, (size_t)(NG * 64 + NG) * 4, stream);
      k_apply_pool<<<1024, 256, 0, stream>>>(B, bnp, batch, pool, cnt);
      k_finalize<<<(NG * 64 + 255) / 256, 256, 0, stream>>>(pool, cnt, out);
    }
  }
}